// Round 1
// 135.263 us; speedup vs baseline: 1.0148x; 1.0148x over previous
//
#include <hip/hip_runtime.h>

// Problem dims (hardcoded per reference setup_inputs):
//   x:   (8, 64, 64, 64)   fp32
//   ref: (8, 64, 128, 128) fp32
//   out: (8, 64, 128, 128) fp32
#define B   8
#define C   64
#define HI  64
#define WI  64
#define HO  128
#define WO  128

using short8 = __attribute__((ext_vector_type(8))) short;
using f32x4  = __attribute__((ext_vector_type(4))) float;
using i32x4  = __attribute__((ext_vector_type(4))) int;

__device__ __forceinline__ float relu(float v) { return v > 0.f ? v : 0.f; }

// round-to-nearest-even f32 -> bf16 (low 16 bits of result)
__device__ __forceinline__ unsigned bf16rne(float x) {
  unsigned u = __float_as_uint(x);
  u += 0x7FFFu + ((u >> 16) & 1u);
  return u >> 16;
}
// pack two f32 -> bf16 pair (lo in bits [15:0], hi in bits [31:16])
__device__ __forceinline__ unsigned packbf(float lo, float hi) {
  unsigned ua = __float_as_uint(lo); ua += 0x7FFFu + ((ua >> 16) & 1u);
  unsigned ub = __float_as_uint(hi); ub += 0x7FFFu + ((ub >> 16) & 1u);
  return (ua >> 16) | (ub & 0xFFFF0000u);
}

// ---------------------------------------------------------------------------
// Fully fused kernel: one block = one output row (b, h). 1024 blocks x 512 thr.
// Phase 1: stage x rows {rlo, r1} packed bf16 + W1(scale-folded) + res
//          half-channel partial sums from ref rows h-1..h+1.
// Phase 2: conv1 MFMA -> y1 tile (f32, LDS, ch-major) + mask corner weights.
// Phase 3: stage ref row h + W2 (overlaying phase-1 buffers), conv2 MFMA,
//          epilogue: out = (sum_corners wc*y1)/den + relu(conv2+bs2).
// No workspace, no second launch, no y1/res global round-trip.
// b = blockIdx&7 keeps each batch's ref/x slices XCD-local (L2 affinity).
// ---------------------------------------------------------------------------
__global__ __launch_bounds__(512, 4) void k_all(
    const float* __restrict__ x,   const float* __restrict__ ref,
    const float* __restrict__ w1,  const float* __restrict__ c1b,
    const float* __restrict__ g1,  const float* __restrict__ b1v,
    const float* __restrict__ m1,  const float* __restrict__ v1,
    const float* __restrict__ w2,  const float* __restrict__ c2b,
    const float* __restrict__ g2,  const float* __restrict__ b2v,
    const float* __restrict__ m2,  const float* __restrict__ v2,
    float* __restrict__ out) {
  __shared__ __align__(16) char stg[26112];
  unsigned*       xP    = (unsigned*)stg;                   // [32][132] c-pair bf16 (phase 1/2)
  unsigned short* W1s   = (unsigned short*)(stg + 16896);   // [64][72] bf16
  unsigned*       refsP = (unsigned*)stg;                   // alias, phase 3
  unsigned short* W2s   = (unsigned short*)(stg + 16896);   // alias, phase 3
  __shared__ __align__(16) float y1c[64][132];  // [ch][rowsel*64 + col], f32
  __shared__ __align__(16) float resr2[3][130][2];  // half-channel partial sums
  __shared__ float s_wc[4][128];
  __shared__ float s_inv[128];
  __shared__ float s_bs1[64];
  __shared__ float s_bs2[64];

  const int bx  = blockIdx.x;
  const int b   = bx & 7;            // XCD-affine
  const int h   = bx >> 3;           // 0..127
  const int tid = threadIdx.x;

  const int rlo = (h >= 1) ? ((h - 1) >> 1) : 0;
  int r1 = rlo + 1; if (r1 > HI - 1) r1 = HI - 1;

  // ---------------- phase 1: stage x, W1, biases, res partials ----------------
  for (int i = tid; i < 1024; i += 512) {     // 32 c-pairs x 32 px-quads (2 rows)
    const int c2 = i >> 5, q = i & 31;
    const int row = (q < 16) ? rlo : r1;
    const int col = (q & 15) * 4;
    const float* sp = x + ((size_t)(b * C + 2 * c2) * HI + row) * WI + col;
    const float4 lo = *(const float4*)sp;
    const float4 hi = *(const float4*)(sp + (size_t)HI * WI);
    uint4 pk;
    pk.x = packbf(lo.x, hi.x); pk.y = packbf(lo.y, hi.y);
    pk.z = packbf(lo.z, hi.z); pk.w = packbf(lo.w, hi.w);
    *(uint4*)&xP[c2 * 132 + q * 4] = pk;
  }
  for (int i = tid; i < 4096; i += 512) {     // W1 scale-folded -> bf16
    const int o = i >> 6;
    const float s = g1[o] * rsqrtf(v1[o] + 1e-5f);
    W1s[o * 72 + (i & 63)] = (unsigned short)bf16rne(w1[i] * s);
  }
  if (tid < 64) {
    float s = g1[tid] * rsqrtf(v1[tid] + 1e-5f);
    s_bs1[tid] = c1b[tid] * s + b1v[tid] - m1[tid] * s;
    s = g2[tid] * rsqrtf(v2[tid] + 1e-5f);
    s_bs2[tid] = c2b[tid] * s + b2v[tid] - m2[tid] * s;
  }
  // res partial sums: 3 rows x 64 px-pairs x {even,odd} channel halves.
  // Accumulation order bit-matches the previous passing kernel:
  // even channels summed ascending, odd channels summed ascending,
  // combined as (even+odd)*(1/64) at mask read.
  if (tid < 384) {
    const int rr = tid >> 7;                  // 0..2
    const int j  = tid & 127;
    const int p  = j >> 1, half = j & 1;      // half: 0=even ch, 1=odd ch
    const int hh = h + rr - 1;
    float sx = 0.f, sy = 0.f;
    if (hh >= 0 && hh < HO) {
      const float* sp = ref + ((size_t)(b * C + half) * HO + hh) * WO + 2 * p;
#pragma unroll
      for (int k = 0; k < 32; ++k) {          // channel = half + 2k, ascending
        const float2 t = *(const float2*)&sp[(size_t)(2 * k) * (HO * WO)];
        sx += t.x; sy += t.y;
      }
    }
    resr2[rr][1 + 2 * p][half] = sx;
    resr2[rr][2 + 2 * p][half] = sy;
  } else if (tid < 396) {                     // zero the 12 border cells
    const int i2 = tid - 384;
    const int rr = i2 >> 2, idx = i2 & 3;
    resr2[rr][(idx & 1) ? 129 : 0][idx >> 1] = 0.f;
  }
  __syncthreads();   // b1

  // ---------------- phase 2: conv1 MFMA -> y1c, mask weights ----------------
  const int wid  = tid >> 6;          // 0..7
  const int lane = tid & 63;
  const int wo = wid & 3, wp = wid >> 2;   // o-tile, px-half
  const int lq = lane >> 4, ln = lane & 15;
  const int ob = wo * 16 + lq * 4;

  {
    const short8 fa0 = *(const short8*)&W1s[(wo * 16 + ln) * 72 + lq * 8];
    const short8 fa1 = *(const short8*)&W1s[(wo * 16 + ln) * 72 + 32 + lq * 8];
    float bs1a[4];
    *(float4*)bs1a = *(const float4*)&s_bs1[ob];
#pragma unroll
    for (int t = 0; t < 4; ++t) {
      const int px = wp * 64 + t * 16 + ln;   // rowsel*64 + col
      i32x4 b0, b1;
#pragma unroll
      for (int r = 0; r < 4; ++r) {
        b0[r] = (int)xP[(lq * 4 + r) * 132 + px];
        b1[r] = (int)xP[(16 + lq * 4 + r) * 132 + px];
      }
      f32x4 a = {0.f, 0.f, 0.f, 0.f};
      a = __builtin_amdgcn_mfma_f32_16x16x32_bf16(fa0, __builtin_bit_cast(short8, b0), a, 0, 0, 0);
      a = __builtin_amdgcn_mfma_f32_16x16x32_bf16(fa1, __builtin_bit_cast(short8, b1), a, 0, 0, 0);
#pragma unroll
      for (int r = 0; r < 4; ++r)
        y1c[ob + r][px] = relu(a[r] + bs1a[r]);
    }
  }

  // mask phase: per-pixel 4 corner weights + invden (threads 0..127)
  if (tid < 128) {
    const int w = tid;
    float u[9];
#pragma unroll
    for (int dh = 0; dh < 3; ++dh)
#pragma unroll
      for (int dw = 0; dw < 3; ++dw) {
        const float2 pr = *(const float2*)&resr2[dh][w + dw][0];
        u[dh * 3 + dw] = (pr.x + pr.y) * (1.f / 64.f);
      }
    float sum = u[0];
#pragma unroll
    for (int k = 1; k < 9; ++k) sum += u[k];
    const float ua = sum * (1.f / 9.f);
    const bool ui = (u[4] - ua) > 0.f;

    const int clo = (w >= 1) ? ((w - 1) >> 1) : 0;
    float den = 0.f;
    float wc0 = 0.f, wc1 = 0.f, wc2 = 0.f, wc3 = 0.f;
#pragma unroll
    for (int dh = 0; dh < 3; ++dh) {
      const int hh = h + dh - 1;
      const bool hv = (hh >= 0) && (hh < HO);
      const int rs = hv ? ((hh >> 1) - rlo) : 0;
#pragma unroll
      for (int dw = 0; dw < 3; ++dw) {
        const bool up = (u[dh * 3 + dw] - ua) > 0.f;
        const float mk = (up == ui) ? 1.f : 0.f;
        den += mk;
        const int ww = w + dw - 1;
        const bool wv = (ww >= 0) && (ww < WO);
        const int cs = wv ? ((ww >> 1) - clo) : 0;
        const float t = (hv && wv) ? mk : 0.f;
        const float t0 = (rs == 0) ? t : 0.f;
        const float t1 = (rs == 1) ? t : 0.f;
        wc0 += (cs == 0) ? t0 : 0.f;
        wc1 += (cs == 1) ? t0 : 0.f;
        wc2 += (cs == 0) ? t1 : 0.f;
        wc3 += (cs == 1) ? t1 : 0.f;
      }
    }
    s_wc[0][w] = wc0; s_wc[1][w] = wc1; s_wc[2][w] = wc2; s_wc[3][w] = wc3;
    s_inv[w] = 1.f / (den + 1e-6f);
  }
  __syncthreads();   // b2: xP/W1s reads done (safe to overlay), mask+y1c written

  // ---------------- phase 3: stage ref row + W2, conv2, epilogue -------------
  for (int i = tid; i < 1024; i += 512) {     // 32 c-pairs x 32 px-quads
    const int c2 = i >> 5, q = i & 31;
    const float* sp = ref + ((size_t)(b * C + 2 * c2) * HO + h) * WO + q * 4;
    const float4 lo = *(const float4*)sp;
    const float4 hi = *(const float4*)(sp + (size_t)HO * WO);
    uint4 pk;
    pk.x = packbf(lo.x, hi.x); pk.y = packbf(lo.y, hi.y);
    pk.z = packbf(lo.z, hi.z); pk.w = packbf(lo.w, hi.w);
    *(uint4*)&refsP[c2 * 132 + q * 4] = pk;
  }
  for (int i = tid; i < 4096; i += 512) {     // W2 scale-folded -> bf16
    const int o = i >> 6;
    const float s = g2[o] * rsqrtf(v2[o] + 1e-5f);
    W2s[o * 72 + (i & 63)] = (unsigned short)bf16rne(w2[i] * s);
  }
  __syncthreads();   // b3

  const short8 fb0 = *(const short8*)&W2s[(wo * 16 + ln) * 72 + lq * 8];
  const short8 fb1 = *(const short8*)&W2s[(wo * 16 + ln) * 72 + 32 + lq * 8];

  f32x4 acc2[4];
#pragma unroll
  for (int t = 0; t < 4; ++t) {
    const int px = wp * 64 + t * 16 + ln;
    i32x4 b0, b1;
#pragma unroll
    for (int r = 0; r < 4; ++r) {
      b0[r] = (int)refsP[(lq * 4 + r) * 132 + px];
      b1[r] = (int)refsP[(16 + lq * 4 + r) * 132 + px];
    }
    acc2[t] = (f32x4){0.f, 0.f, 0.f, 0.f};
    acc2[t] = __builtin_amdgcn_mfma_f32_16x16x32_bf16(fb0, __builtin_bit_cast(short8, b0), acc2[t], 0, 0, 0);
    acc2[t] = __builtin_amdgcn_mfma_f32_16x16x32_bf16(fb1, __builtin_bit_cast(short8, b1), acc2[t], 0, 0, 0);
  }

  float bs2a[4];
  *(float4*)bs2a = *(const float4*)&s_bs2[ob];

#pragma unroll
  for (int t = 0; t < 4; ++t) {
    const int px = wp * 64 + t * 16 + ln;
    const int cl = (px >= 1) ? ((px - 1) >> 1) : 0;
    int c1 = cl + 1; if (c1 > WI - 1) c1 = WI - 1;
    const float wc0 = s_wc[0][px], wc1 = s_wc[1][px];
    const float wc2 = s_wc[2][px], wc3 = s_wc[3][px];
    const float inv = s_inv[px];

    float* op = out + (size_t)(b * C + ob) * (HO * WO) + h * WO + px;
#pragma unroll
    for (int r = 0; r < 4; ++r) {
      const float n = wc0 * y1c[ob + r][cl]      + wc1 * y1c[ob + r][c1]
                    + wc2 * y1c[ob + r][64 + cl] + wc3 * y1c[ob + r][64 + c1];
      op[(size_t)r * (HO * WO)] = n * inv + relu(acc2[t][r] + bs2a[r]);
    }
  }
}

// ---------------------------------------------------------------------------
extern "C" void kernel_launch(void* const* d_in, const int* in_sizes, int n_in,
                              void* d_out, int out_size, void* d_ws, size_t ws_size,
                              hipStream_t stream) {
  (void)in_sizes; (void)n_in; (void)out_size; (void)d_ws; (void)ws_size;
  const float* x   = (const float*)d_in[0];
  const float* ref = (const float*)d_in[1];
  const float* w1  = (const float*)d_in[2];
  const float* c1b = (const float*)d_in[3];
  const float* g1  = (const float*)d_in[4];
  const float* b1  = (const float*)d_in[5];
  const float* m1  = (const float*)d_in[6];
  const float* v1  = (const float*)d_in[7];
  const float* w2  = (const float*)d_in[8];
  const float* c2b = (const float*)d_in[9];
  const float* g2  = (const float*)d_in[10];
  const float* b2  = (const float*)d_in[11];
  const float* m2  = (const float*)d_in[12];
  const float* v2  = (const float*)d_in[13];
  float* out = (float*)d_out;

  k_all<<<B * HO, 512, 0, stream>>>(x, ref, w1, c1b, g1, b1, m1, v1,
                                    w2, c2b, g2, b2, m2, v2, out);
}